// Round 4
// baseline (559.820 us; speedup 1.0000x reference)
//
#include <hip/hip_runtime.h>

#define LSEQ 1024

typedef __attribute__((ext_vector_type(8))) short bf16x8;
typedef __attribute__((ext_vector_type(4))) float f32x4;

__device__ __forceinline__ float gelu_f(float x){
    return 0.5f*x*(1.0f+erff(x*0.7071067811865476f));
}

__device__ __forceinline__ unsigned f2bf1(float x){
    unsigned u = __float_as_uint(x);
    return (u + 0x7fffu + ((u>>16)&1u)) >> 16;
}
__device__ __forceinline__ unsigned packbf(float lo, float hi){
    return f2bf1(lo) | (f2bf1(hi)<<16);
}

// ---------------------------------------------------------------------------
// MFMA GEMM: C[n] = A (M,K) x transform(B[n]) (K,1024); transform =
// optional groupnorm (from global stats) + affine + optional gelu, fused into
// bf16 LDS staging. 64x64 tile/block; wave = 16m x 64l; K chunked by 32.
// mfma_f32_16x16x32_bf16: A-frag A[m=lane&15][k=quad*8+j], B-frag
// B[k=quad*8+j][n=lane&15], D row=quad*4+reg col=lane&15 (verified layouts).
// LDS rows stride 40 shorts (80 B): 2-way bank aliasing only (free).
// Accumulates per-sample sum/sumsq of outputs into out_stats.
// ---------------------------------------------------------------------------
__global__ __launch_bounds__(256,4) void gemm_mfma(
    const float* __restrict__ A,
    const float* __restrict__ B,
    float* __restrict__ C,
    const float* __restrict__ in_stats,
    const float* __restrict__ gw,
    const float* __restrict__ gb,
    float in_cnt_inv, int apply_gelu,
    int M, int K,
    float* __restrict__ out_stats)
{
    __shared__ short As[64*40];   // [m][k], 5120 B
    __shared__ short Bs[64*40];   // [l][k], 5120 B

    int tid = threadIdx.x;
    int n  = blockIdx.z;
    int n0 = blockIdx.x*64;       // l offset
    int m0 = blockIdx.y*64;       // output-channel offset
    int wave = tid>>6, lane = tid&63;
    int col = lane&15, quad = lane>>4;

    float mu=0.f, istd=1.f;
    if (in_stats){
        float s1 = in_stats[2*n], s2 = in_stats[2*n+1];
        mu = s1*in_cnt_inv;
        float var = s2*in_cnt_inv - mu*mu;
        istd = rsqrtf(var + 1e-5f);
    }

    const float* Bn = B + (size_t)n*K*LSEQ;

    // staging assignments
    int sm = tid>>2,  sk = (tid&3)*8;   // A: row sm, k sk..sk+7
    int sl = tid&63,  scg = tid>>6;     // B: l sl, channels scg*8..+7

    f32x4 acc[4];
    #pragma unroll
    for(int t=0;t<4;t++) acc[t] = (f32x4){0.f,0.f,0.f,0.f};

    for(int k0=0; k0<K; k0+=32){
        // ---- stage A tile (64 x 32) as bf16 ----
        {
            const float* ap = A + (size_t)(m0+sm)*K + k0 + sk;
            float4 a0 = *(const float4*)(ap);
            float4 a1 = *(const float4*)(ap+4);
            uint4 pa;
            pa.x = packbf(a0.x,a0.y); pa.y = packbf(a0.z,a0.w);
            pa.z = packbf(a1.x,a1.y); pa.w = packbf(a1.z,a1.w);
            *(uint4*)&As[sm*40 + sk] = pa;
        }
        // ---- stage B tile (32 x 64) transposed -> [l][k], fused transform ----
        {
            float bv[8];
            #pragma unroll
            for(int cc=0;cc<8;cc++){
                int c = k0 + scg*8 + cc;
                float x = Bn[(size_t)c*LSEQ + n0 + sl];
                float w_=1.f, b_=0.f;
                if (gw){ w_=gw[c]; b_=gb[c]; }
                float t = (x-mu)*istd*w_ + b_;
                if (apply_gelu) t = gelu_f(t);
                bv[cc]=t;
            }
            uint4 pb;
            pb.x = packbf(bv[0],bv[1]); pb.y = packbf(bv[2],bv[3]);
            pb.z = packbf(bv[4],bv[5]); pb.w = packbf(bv[6],bv[7]);
            *(uint4*)&Bs[sl*40 + scg*8] = pb;
        }
        __syncthreads();

        bf16x8 af = *(bf16x8*)&As[(wave*16+col)*40 + quad*8];
        #pragma unroll
        for(int t=0;t<4;t++){
            bf16x8 bf = *(bf16x8*)&Bs[(t*16+col)*40 + quad*8];
            acc[t] = __builtin_amdgcn_mfma_f32_16x16x32_bf16(af, bf, acc[t], 0,0,0);
        }
        __syncthreads();
    }

    // ---- epilogue: store + per-sample stats ----
    size_t cbase = (size_t)n*M*LSEQ;
    float lsum=0.f, lsq=0.f;
    #pragma unroll
    for(int t=0;t<4;t++){
        #pragma unroll
        for(int r=0;r<4;r++){
            int m = m0 + wave*16 + quad*4 + r;
            int l = n0 + t*16 + col;
            float v = acc[t][r];
            C[cbase + (size_t)m*LSEQ + l] = v;
            lsum += v; lsq += v*v;
        }
    }
    float* scr = (float*)As;
    scr[tid] = lsum; scr[256+tid] = lsq;
    __syncthreads();
    for(int s=128;s>0;s>>=1){
        if(tid<s){ scr[tid]+=scr[tid+s]; scr[256+tid]+=scr[256+tid+s]; }
        __syncthreads();
    }
    if(tid==0){
        atomicAdd(&out_stats[2*n],   scr[0]);
        atomicAdd(&out_stats[2*n+1], scr[256]);
    }
}

// ---------------------------------------------------------------------------
// Per-head analytic LayerNorm istd for the LxL logit map:
//   sum(s)  = sum_q . sum_k ;  sum(s^2) = sum_l q^T (sum_m k k^T) q
// ---------------------------------------------------------------------------
__global__ __launch_bounds__(256) void head_stats(
    const float* __restrict__ qkv,
    const float* __restrict__ s_qkv,
    const float* __restrict__ gq_w, const float* __restrict__ gq_b,
    float* __restrict__ istd_head)
{
    __shared__ float Ks[16*260];
    __shared__ float Ml[256];
    __shared__ float sumk[16];
    __shared__ float sumq[16];
    __shared__ double dred[256];

    int head = blockIdx.x;
    int n = head>>3, h = head&7;
    int tid = threadIdx.x;

    float s1 = s_qkv[2*n], s2v = s_qkv[2*n+1];
    float mu  = s1*(1.f/524288.f);
    float var = s2v*(1.f/524288.f) - mu*mu;
    float istd = rsqrtf(var + 1e-5f);

    const float* base = qkv + (size_t)n*512*LSEQ;
    int i_ = tid>>4, j_ = tid&15;
    float Mij = 0.f;
    float skp = 0.f;

    for(int m0=0;m0<1024;m0+=256){
        #pragma unroll
        for(int c=0;c<16;c++){
            int ch = 128 + h*16 + c;
            float x = base[(size_t)ch*LSEQ + m0 + tid];
            Ks[c*260+tid] = (x-mu)*istd*gq_w[ch]+gq_b[ch];
        }
        __syncthreads();
        for(int mm=0;mm<256;mm++)
            Mij += Ks[i_*260+mm]*Ks[j_*260+mm];
        if (tid<16){
            for(int mm=0;mm<256;mm++) skp += Ks[tid*260+mm];
        }
        __syncthreads();
    }
    Ml[tid] = Mij;
    if(tid<16){ sumk[tid]=skp; sumq[tid]=0.f; }
    __syncthreads();

    double S2p = 0.0;
    float sqp[16];
    #pragma unroll
    for(int c=0;c<16;c++) sqp[c]=0.f;

    for(int m0=0;m0<1024;m0+=256){
        #pragma unroll
        for(int c=0;c<16;c++){
            int ch = h*16 + c;
            float x = base[(size_t)ch*LSEQ + m0 + tid];
            Ks[c*260+tid] = (x-mu)*istd*gq_w[ch]+gq_b[ch];
        }
        __syncthreads();
        float q[16];
        #pragma unroll
        for(int c=0;c<16;c++) q[c]=Ks[c*260+tid];
        float accf = 0.f;
        #pragma unroll
        for(int i=0;i<16;i++){
            float t=0.f;
            #pragma unroll
            for(int j=0;j<16;j++) t += Ml[i*16+j]*q[j];
            accf += t*q[i];
        }
        S2p += (double)accf;
        #pragma unroll
        for(int c=0;c<16;c++) sqp[c]+=q[c];
        __syncthreads();
    }
    #pragma unroll
    for(int c=0;c<16;c++) atomicAdd(&sumq[c], sqp[c]);
    dred[tid] = S2p;
    __syncthreads();
    for(int s=128;s>0;s>>=1){
        if(tid<s) dred[tid]+=dred[tid+s];
        __syncthreads();
    }
    if(tid==0){
        double S1=0.0;
        for(int c=0;c<16;c++) S1 += (double)sumq[c]*(double)sumk[c];
        double cnt = 1048576.0;
        double mean = S1/cnt;
        double v2 = dred[0]/cnt - mean*mean;
        if(v2 < 0.0) v2 = 0.0;
        istd_head[head] = (float)(1.0/sqrt(v2 + 1e-5));
    }
}

// ---------------------------------------------------------------------------
// Attention v3: single main pass with Cauchy-Schwarz shift bound
// (softmax is shift-exact; only underflow matters, slack is a few sigma).
// 512-thr block = (head, 128 rows). 16-lane group owns 4 rows:
//   dot phase: lane = one of 16 m-slots, computes p[4] (no duplicated dots)
//   PV phase: lane = (qq,dq) accumulates dims dq*8..+7 for m-slots qq*4..+3,
//             p obtained via __shfl (register exchange, no LDS).
// ---------------------------------------------------------------------------
__global__ __launch_bounds__(512) void attn_kernel(
    const float* __restrict__ qkv,
    const float* __restrict__ s_qkv,
    const float* __restrict__ gq_w, const float* __restrict__ gq_b,
    const float* __restrict__ istd_head,
    float* __restrict__ out,
    float* __restrict__ out_stats)
{
    __shared__ float Kc[256*20];   // 16 data + pad (row-major [m][c])
    __shared__ float Vc[256*36];   // 32 data + pad (row-major [m][d])
    __shared__ float sred[8];

    int b = blockIdx.x;
    int head = b>>3, rb = b&7;
    int n = head>>3, h = head&7;
    int tid = threadIdx.x;
    int rg = tid>>4, lane4 = tid&15;
    int qq = lane4&3, dq = lane4>>2;
    int l0 = rb*128;
    int lr = l0 + rg*4;
    int lane = tid&63;
    int gbase = lane&48;

    const float* base = qkv + (size_t)n*512*LSEQ;
    float s1 = s_qkv[2*n], s2v = s_qkv[2*n+1];
    float mu  = s1*(1.f/524288.f);
    float var = s2v*(1.f/524288.f) - mu*mu;
    float istd = rsqrtf(var + 1e-5f);
    float ih = istd_head[head];

    // q fragments, ih folded in; accumulate row norms for the bound
    float q[4][16];
    float qn2[4] = {0.f,0.f,0.f,0.f};
    #pragma unroll
    for(int c=0;c<16;c++){
        int ch = h*16+c;
        float w_ = gq_w[ch]*istd*ih, b_ = (gq_b[ch]-mu*istd*gq_w[ch])*ih;
        #pragma unroll
        for(int r=0;r<4;r++){
            float x = base[(size_t)ch*LSEQ + lr + r];
            float qv = x*w_ + b_;
            q[r][c] = qv;
            qn2[r] += qv*qv;
        }
    }

    // K max-norm prepass (2 rows/thread)
    float kn2max = 0.f;
    for(int mr=tid; mr<1024; mr+=512){
        float s = 0.f;
        #pragma unroll
        for(int c=0;c<16;c++){
            int ch = 128+h*16+c;
            float x = base[(size_t)ch*LSEQ + mr];
            float kv = (x-mu)*istd*gq_w[ch]+gq_b[ch];
            s += kv*kv;
        }
        kn2max = fmaxf(kn2max, s);
    }
    #pragma unroll
    for(int d=1; d<64; d<<=1) kn2max = fmaxf(kn2max, __shfl_xor(kn2max,d));
    if(lane==0) sred[tid>>6] = kn2max;
    __syncthreads();
    float km = sred[0];
    #pragma unroll
    for(int w=1;w<8;w++) km = fmaxf(km, sred[w]);
    float kmax = sqrtf(km);
    float bound[4];
    #pragma unroll
    for(int r=0;r<4;r++) bound[r] = sqrtf(qn2[r])*kmax;

    float o[4][8];
    #pragma unroll
    for(int r=0;r<4;r++)
        #pragma unroll
        for(int d=0;d<8;d++) o[r][d]=0.f;
    float ssum[4] = {0.f,0.f,0.f,0.f};

    for(int m0=0;m0<1024;m0+=256){
        if(tid<256){
            #pragma unroll
            for(int c=0;c<16;c++){
                int ch = 128+h*16+c;
                float x = base[(size_t)ch*LSEQ + m0 + tid];
                Kc[tid*20+c] = (x-mu)*istd*gq_w[ch]+gq_b[ch];
            }
        }
        {
            int vrow = tid&255, dh = (tid>>8)<<4;
            #pragma unroll
            for(int dd=0;dd<16;dd++){
                int ch = 256+h*32+dh+dd;
                float x = base[(size_t)ch*LSEQ + m0 + vrow];
                Vc[vrow*36+dh+dd] = (x-mu)*istd*gq_w[ch]+gq_b[ch];
            }
        }
        __syncthreads();

        for(int j=0;j<16;j++){
            int mm = lane4 + j*16;
            int m = m0 + mm;
            const float4* k4 = (const float4*)(Kc + mm*20);
            float4 k0=k4[0],k1=k4[1],k2=k4[2],k3=k4[3];
            float p[4];
            #pragma unroll
            for(int r=0;r<4;r++){
                float s = q[r][0]*k0.x+q[r][1]*k0.y+q[r][2]*k0.z+q[r][3]*k0.w
                        + q[r][4]*k1.x+q[r][5]*k1.y+q[r][6]*k1.z+q[r][7]*k1.w
                        + q[r][8]*k2.x+q[r][9]*k2.y+q[r][10]*k2.z+q[r][11]*k2.w
                        + q[r][12]*k3.x+q[r][13]*k3.y+q[r][14]*k3.z+q[r][15]*k3.w;
                float pv = __expf(s - bound[r]);
                pv = (m == lr+r) ? 0.f : pv;
                p[r] = pv;
                ssum[r] += pv;
            }
            #pragma unroll
            for(int i=0;i<4;i++){
                int ml = qq*4 + i;
                int src = gbase + ml;
                float pr0 = __shfl(p[0], src);
                float pr1 = __shfl(p[1], src);
                float pr2 = __shfl(p[2], src);
                float pr3 = __shfl(p[3], src);
                const float4* vv = (const float4*)(Vc + (ml + j*16)*36 + dq*8);
                float4 va = vv[0], vb = vv[1];
                o[0][0]+=pr0*va.x; o[0][1]+=pr0*va.y; o[0][2]+=pr0*va.z; o[0][3]+=pr0*va.w;
                o[0][4]+=pr0*vb.x; o[0][5]+=pr0*vb.y; o[0][6]+=pr0*vb.z; o[0][7]+=pr0*vb.w;
                o[1][0]+=pr1*va.x; o[1][1]+=pr1*va.y; o[1][2]+=pr1*va.z; o[1][3]+=pr1*va.w;
                o[1][4]+=pr1*vb.x; o[1][5]+=pr1*vb.y; o[1][6]+=pr1*vb.z; o[1][7]+=pr1*vb.w;
                o[2][0]+=pr2*va.x; o[2][1]+=pr2*va.y; o[2][2]+=pr2*va.z; o[2][3]+=pr2*va.w;
                o[2][4]+=pr2*vb.x; o[2][5]+=pr2*vb.y; o[2][6]+=pr2*vb.z; o[2][7]+=pr2*vb.w;
                o[3][0]+=pr3*va.x; o[3][1]+=pr3*va.y; o[3][2]+=pr3*va.z; o[3][3]+=pr3*va.w;
                o[3][4]+=pr3*vb.x; o[3][5]+=pr3*vb.y; o[3][6]+=pr3*vb.z; o[3][7]+=pr3*vb.w;
            }
        }
        __syncthreads();
    }

    // ssum: every lane covered distinct m-slots -> reduce over all 4 lane bits
    #pragma unroll
    for(int r=0;r<4;r++){
        ssum[r] += __shfl_xor(ssum[r],1);
        ssum[r] += __shfl_xor(ssum[r],2);
        ssum[r] += __shfl_xor(ssum[r],4);
        ssum[r] += __shfl_xor(ssum[r],8);
    }
    // o: partials across qq (lane bits 0,1)
    #pragma unroll
    for(int r=0;r<4;r++)
        #pragma unroll
        for(int d=0;d<8;d++){
            float t = o[r][d];
            t += __shfl_xor(t,1);
            t += __shfl_xor(t,2);
            o[r][d] = t;
        }

    float* osm = Kc;   // 128*33 floats < 5120, free after barrier above
    if(qq==0){
        #pragma unroll
        for(int r=0;r<4;r++){
            float iv = 1.f/ssum[r];
            #pragma unroll
            for(int dd=0;dd<8;dd++)
                osm[(rg*4+r)*33 + dq*8+dd] = o[r][dd]*iv;
        }
    }
    __syncthreads();

    float lsum=0.f, lsq=0.f;
    #pragma unroll
    for(int t=0;t<8;t++){
        int idx = t*512 + tid;
        int d = idx>>7, ll = idx&127;
        float y = osm[ll*33 + d];
        out[(size_t)n*262144 + (size_t)(h*32+d)*LSEQ + l0+ll] = y;
        lsum += y; lsq += y*y;
    }
    float* red = Vc;
    red[tid]=lsum; red[512+tid]=lsq;
    __syncthreads();
    for(int s=256;s>0;s>>=1){
        if(tid<s){ red[tid]+=red[tid+s]; red[512+tid]+=red[512+tid+s]; }
        __syncthreads();
    }
    if(tid==0){
        atomicAdd(&out_stats[2*n],   red[0]);
        atomicAdd(&out_stats[2*n+1], red[512]);
    }
}

// ---------------------------------------------------------------------------
// out = gelu(resid + groupnorm(x)) elementwise; c = channel of element.
// ---------------------------------------------------------------------------
__global__ __launch_bounds__(256) void ew_resid(
    const float* __restrict__ resid, const float* __restrict__ x,
    const float* __restrict__ stats,
    const float* __restrict__ gw, const float* __restrict__ gb,
    float cnt_inv, float* __restrict__ out)
{
    int idx = blockIdx.x*256 + threadIdx.x;   // float4 index
    int n = idx >> 16;                        // 65536 float4 per sample
    int c = (idx >> 8) & 255;
    float ss = stats[2*n], s2 = stats[2*n+1];
    float mu = ss*cnt_inv;
    float var = s2*cnt_inv - mu*mu;
    float istd = rsqrtf(var + 1e-5f);
    float w_ = gw[c], b_ = gb[c];
    float4 xv = ((const float4*)x)[idx];
    float4 rv = ((const float4*)resid)[idx];
    float4 ov;
    ov.x = gelu_f(rv.x + ((xv.x-mu)*istd*w_+b_));
    ov.y = gelu_f(rv.y + ((xv.y-mu)*istd*w_+b_));
    ov.z = gelu_f(rv.z + ((xv.z-mu)*istd*w_+b_));
    ov.w = gelu_f(rv.w + ((xv.w-mu)*istd*w_+b_));
    ((float4*)out)[idx] = ov;
}

// ---------------------------------------------------------------------------
extern "C" void kernel_launch(void* const* d_in, const int* in_sizes, int n_in,
                              void* d_out, int out_size, void* d_ws, size_t ws_size,
                              hipStream_t stream) {
    const float* f     = (const float*)d_in[0];
    const float* w_z   = (const float*)d_in[1];
    const float* gz_w  = (const float*)d_in[2];
    const float* gz_b  = (const float*)d_in[3];
    const float* w_qkv = (const float*)d_in[4];
    const float* gq_w  = (const float*)d_in[5];
    const float* gq_b  = (const float*)d_in[6];
    const float* w_out = (const float*)d_in[7];
    const float* go_w  = (const float*)d_in[8];
    const float* go_b  = (const float*)d_in[9];
    const float* w_f1  = (const float*)d_in[10];
    const float* g1_w  = (const float*)d_in[11];
    const float* g1_b  = (const float*)d_in[12];
    const float* w_f2  = (const float*)d_in[13];
    const float* g2_w  = (const float*)d_in[14];
    const float* g2_b  = (const float*)d_in[15];

    float* ws = (float*)d_ws;
    float* stats = ws;                 // 256 floats
    float* s_z    = stats + 0;
    float* s_qkv  = stats + 16;
    float* s_attn = stats + 32;
    float* s_x    = stats + 48;
    float* s_h1   = stats + 64;
    float* s_h2   = stats + 80;
    float* istdh  = stats + 96;        // 64
    const size_t SM = (size_t)256*1024;   // per-sample 256-ch tensor
    float* buf0 = ws + 256;            // 8*SM  : z0 -> attn_out -> f1 (buf3 alias)
    float* buf1 = buf0 + 8*SM;         // 8*2SM : qkv -> h1pre
    float* buf2 = buf1 + 16*SM;        // 8*SM  : x -> h2pre
    float* buf3 = buf0;                // f1 aliases buf0 (dead after K4)
    float* outp = (float*)d_out;

    hipMemsetAsync(stats, 0, 256*sizeof(float), stream);

    dim3 blk(256);
    // z0 = w_z @ gelu(f)
    gemm_mfma<<<dim3(16,4,8),blk,0,stream>>>(w_z, f, buf0,
        nullptr, nullptr, nullptr, 0.f, 1, 256, 256, s_z);
    // qkv = w_qkv @ gelu(gn(z0))
    gemm_mfma<<<dim3(16,8,8),blk,0,stream>>>(w_qkv, buf0, buf1,
        s_z, gz_w, gz_b, 1.f/262144.f, 1, 512, 256, s_qkv);
    // analytic per-head logit-LN istd
    head_stats<<<64,blk,0,stream>>>(buf1, s_qkv, gq_w, gq_b, istdh);
    // attention -> attn_out (overwrites z0)
    attn_kernel<<<512,dim3(512),0,stream>>>(buf1, s_qkv, gq_w, gq_b, istdh, buf0, s_attn);
    // x = w_out @ gelu(ln(attn_out))
    gemm_mfma<<<dim3(16,4,8),blk,0,stream>>>(w_out, buf0, buf2,
        s_attn, nullptr, nullptr, 1.f/262144.f, 1, 256, 256, s_x);
    // f1 = gelu(f + gn_go(x))   (writes over attn_out region)
    ew_resid<<<2048,blk,0,stream>>>(f, buf2, s_x, go_w, go_b, 1.f/262144.f, buf3);
    // h1 = w_ffn1 @ f1
    gemm_mfma<<<dim3(16,8,8),blk,0,stream>>>(w_f1, buf3, buf1,
        nullptr, nullptr, nullptr, 0.f, 0, 512, 256, s_h1);
    // h2 = w_ffn2 @ gelu(gn_g1(h1))
    gemm_mfma<<<dim3(16,4,8),blk,0,stream>>>(w_f2, buf1, buf2,
        s_h1, g1_w, g1_b, 1.f/524288.f, 1, 256, 512, s_h2);
    // out = gelu(f1 + gn_g2(h2))
    ew_resid<<<2048,blk,0,stream>>>(buf3, buf2, s_h2, g2_w, g2_b, 1.f/262144.f, outp);
}

// Round 6
// 471.440 us; speedup vs baseline: 1.1875x; 1.1875x over previous
//
#include <hip/hip_runtime.h>

#define LSEQ 1024

typedef __attribute__((ext_vector_type(8))) short bf16x8;
typedef __attribute__((ext_vector_type(4))) float f32x4;

__device__ __forceinline__ float gelu_f(float x){
    return 0.5f*x*(1.0f+erff(x*0.7071067811865476f));
}

__device__ __forceinline__ unsigned f2bf1(float x){
    unsigned u = __float_as_uint(x);
    return (u + 0x7fffu + ((u>>16)&1u)) >> 16;
}
__device__ __forceinline__ unsigned packbf(float lo, float hi){
    return f2bf1(lo) | (f2bf1(hi)<<16);
}

// ---------------------------------------------------------------------------
// MFMA GEMM: C[n] = A (M,K) x transform(B[n]) (K,1024); transform =
// optional groupnorm (from global stats) + affine + optional gelu, fused into
// bf16 LDS staging. 64x64 tile/block. Accumulates per-sample sum/sumsq.
// ---------------------------------------------------------------------------
__global__ __launch_bounds__(256,4) void gemm_mfma(
    const float* __restrict__ A,
    const float* __restrict__ B,
    float* __restrict__ C,
    const float* __restrict__ in_stats,
    const float* __restrict__ gw,
    const float* __restrict__ gb,
    float in_cnt_inv, int apply_gelu,
    int M, int K,
    float* __restrict__ out_stats)
{
    __shared__ short As[64*40];   // [m][k]
    __shared__ short Bs[64*40];   // [l][k]

    int tid = threadIdx.x;
    int n  = blockIdx.z;
    int n0 = blockIdx.x*64;       // l offset
    int m0 = blockIdx.y*64;       // output-channel offset
    int wave = tid>>6, lane = tid&63;
    int col = lane&15, quad = lane>>4;

    float mu=0.f, istd=1.f;
    if (in_stats){
        float s1 = in_stats[2*n], s2 = in_stats[2*n+1];
        mu = s1*in_cnt_inv;
        float var = s2*in_cnt_inv - mu*mu;
        istd = rsqrtf(var + 1e-5f);
    }

    const float* Bn = B + (size_t)n*K*LSEQ;

    int sm = tid>>2,  sk = (tid&3)*8;   // A: row sm, k sk..sk+7
    int sl = tid&63,  scg = tid>>6;     // B: l sl, channels scg*8..+7

    f32x4 acc[4];
    #pragma unroll
    for(int t=0;t<4;t++) acc[t] = (f32x4){0.f,0.f,0.f,0.f};

    for(int k0=0; k0<K; k0+=32){
        {
            const float* ap = A + (size_t)(m0+sm)*K + k0 + sk;
            float4 a0 = *(const float4*)(ap);
            float4 a1 = *(const float4*)(ap+4);
            uint4 pa;
            pa.x = packbf(a0.x,a0.y); pa.y = packbf(a0.z,a0.w);
            pa.z = packbf(a1.x,a1.y); pa.w = packbf(a1.z,a1.w);
            *(uint4*)&As[sm*40 + sk] = pa;
        }
        {
            float bv[8];
            #pragma unroll
            for(int cc=0;cc<8;cc++){
                int c = k0 + scg*8 + cc;
                float x = Bn[(size_t)c*LSEQ + n0 + sl];
                float w_=1.f, b_=0.f;
                if (gw){ w_=gw[c]; b_=gb[c]; }
                float t = (x-mu)*istd*w_ + b_;
                if (apply_gelu) t = gelu_f(t);
                bv[cc]=t;
            }
            uint4 pb;
            pb.x = packbf(bv[0],bv[1]); pb.y = packbf(bv[2],bv[3]);
            pb.z = packbf(bv[4],bv[5]); pb.w = packbf(bv[6],bv[7]);
            *(uint4*)&Bs[sl*40 + scg*8] = pb;
        }
        __syncthreads();

        bf16x8 af = *(bf16x8*)&As[(wave*16+col)*40 + quad*8];
        #pragma unroll
        for(int t=0;t<4;t++){
            bf16x8 bf = *(bf16x8*)&Bs[(t*16+col)*40 + quad*8];
            acc[t] = __builtin_amdgcn_mfma_f32_16x16x32_bf16(af, bf, acc[t], 0,0,0);
        }
        __syncthreads();
    }

    size_t cbase = (size_t)n*M*LSEQ;
    float lsum=0.f, lsq=0.f;
    #pragma unroll
    for(int t=0;t<4;t++){
        #pragma unroll
        for(int r=0;r<4;r++){
            int m = m0 + wave*16 + quad*4 + r;
            int l = n0 + t*16 + col;
            float v = acc[t][r];
            C[cbase + (size_t)m*LSEQ + l] = v;
            lsum += v; lsq += v*v;
        }
    }
    float* scr = (float*)As;
    scr[tid] = lsum; scr[256+tid] = lsq;
    __syncthreads();
    for(int s=128;s>0;s>>=1){
        if(tid<s){ scr[tid]+=scr[tid+s]; scr[256+tid]+=scr[256+tid+s]; }
        __syncthreads();
    }
    if(tid==0){
        atomicAdd(&out_stats[2*n],   scr[0]);
        atomicAdd(&out_stats[2*n+1], scr[256]);
    }
}

// ---------------------------------------------------------------------------
// Per-head analytic LayerNorm istd for the LxL logit map:
//   sum(s)  = sum_q . sum_k ;  sum(s^2) = sum_l q^T (sum_m k k^T) q
// ---------------------------------------------------------------------------
__global__ __launch_bounds__(256) void head_stats(
    const float* __restrict__ qkv,
    const float* __restrict__ s_qkv,
    const float* __restrict__ gq_w, const float* __restrict__ gq_b,
    float* __restrict__ istd_head)
{
    __shared__ float Ks[16*260];
    __shared__ float Ml[256];
    __shared__ float sumk[16];
    __shared__ float sumq[16];
    __shared__ double dred[256];

    int head = blockIdx.x;
    int n = head>>3, h = head&7;
    int tid = threadIdx.x;

    float s1 = s_qkv[2*n], s2v = s_qkv[2*n+1];
    float mu  = s1*(1.f/524288.f);
    float var = s2v*(1.f/524288.f) - mu*mu;
    float istd = rsqrtf(var + 1e-5f);

    const float* base = qkv + (size_t)n*512*LSEQ;
    int i_ = tid>>4, j_ = tid&15;
    float Mij = 0.f;
    float skp = 0.f;

    for(int m0=0;m0<1024;m0+=256){
        #pragma unroll
        for(int c=0;c<16;c++){
            int ch = 128 + h*16 + c;
            float x = base[(size_t)ch*LSEQ + m0 + tid];
            Ks[c*260+tid] = (x-mu)*istd*gq_w[ch]+gq_b[ch];
        }
        __syncthreads();
        for(int mm=0;mm<256;mm++)
            Mij += Ks[i_*260+mm]*Ks[j_*260+mm];
        if (tid<16){
            for(int mm=0;mm<256;mm++) skp += Ks[tid*260+mm];
        }
        __syncthreads();
    }
    Ml[tid] = Mij;
    if(tid<16){ sumk[tid]=skp; sumq[tid]=0.f; }
    __syncthreads();

    double S2p = 0.0;
    float sqp[16];
    #pragma unroll
    for(int c=0;c<16;c++) sqp[c]=0.f;

    for(int m0=0;m0<1024;m0+=256){
        #pragma unroll
        for(int c=0;c<16;c++){
            int ch = h*16 + c;
            float x = base[(size_t)ch*LSEQ + m0 + tid];
            Ks[c*260+tid] = (x-mu)*istd*gq_w[ch]+gq_b[ch];
        }
        __syncthreads();
        float q[16];
        #pragma unroll
        for(int c=0;c<16;c++) q[c]=Ks[c*260+tid];
        float accf = 0.f;
        #pragma unroll
        for(int i=0;i<16;i++){
            float t=0.f;
            #pragma unroll
            for(int j=0;j<16;j++) t += Ml[i*16+j]*q[j];
            accf += t*q[i];
        }
        S2p += (double)accf;
        #pragma unroll
        for(int c=0;c<16;c++) sqp[c]+=q[c];
        __syncthreads();
    }
    #pragma unroll
    for(int c=0;c<16;c++) atomicAdd(&sumq[c], sqp[c]);
    dred[tid] = S2p;
    __syncthreads();
    for(int s=128;s>0;s>>=1){
        if(tid<s) dred[tid]+=dred[tid+s];
        __syncthreads();
    }
    if(tid==0){
        double S1=0.0;
        for(int c=0;c<16;c++) S1 += (double)sumq[c]*(double)sumk[c];
        double cnt = 1048576.0;
        double mean = S1/cnt;
        double v2 = dred[0]/cnt - mean*mean;
        if(v2 < 0.0) v2 = 0.0;
        istd_head[head] = (float)(1.0/sqrt(v2 + 1e-5));
    }
}

// ---------------------------------------------------------------------------
// Attention v4: MFMA flash attention. Block = (head, 128 Q-rows), 256 thr
// (4 waves). Per 128-m chunk:
//   S^T = K.Q^T via mfma_16x16x32_bf16 (c-dim 16 real + 16 zero-pad).
//     S^T C-layout: lane holds 4 consecutive m at fixed Q-row -> exp via
//     Cauchy-Schwarz bound shift (shift-exact softmax), bf16 pack, one
//     ds_write_b64 per tile into Ps[row][m] (wave-local rows, no exchange).
//   PV: out += P.V via mfma (K=m); A-frag from Ps, B-frag from Vs[d][m].
// ssum per row accumulated in-register, reduced across quads via shfl.
// Epilogue restages through LDS for coalesced writes + stats.
// ---------------------------------------------------------------------------
__global__ __launch_bounds__(256) void attn_kernel(
    const float* __restrict__ qkv,
    const float* __restrict__ s_qkv,
    const float* __restrict__ gq_w, const float* __restrict__ gq_b,
    const float* __restrict__ istd_head,
    float* __restrict__ out,
    float* __restrict__ out_stats)
{
    __shared__ short Qs[128*40];    // [row][c], c 0..15 real, 16..31 zero
    __shared__ short Ks[128*40];    // [m][c],   same padding
    __shared__ short Vs[32*136];    // [d][m]
    __shared__ short Ps[128*152];   // [row][m] bf16 P
    __shared__ float bounds_l[128];
    __shared__ float issum_l[128];
    __shared__ float sred4[4];

    int b = blockIdx.x;
    int head = b>>3, rb = b&7;
    int n = head>>3, h = head&7;
    int tid = threadIdx.x;
    int wv = tid>>6, lane = tid&63;
    int col = lane&15, quad = lane>>4;
    int l0 = rb*128;

    const float* base = qkv + (size_t)n*512*LSEQ;
    float s1 = s_qkv[2*n], s2v = s_qkv[2*n+1];
    float mu  = s1*(1.f/524288.f);
    float var = s2v*(1.f/524288.f) - mu*mu;
    float istd = rsqrtf(var + 1e-5f);
    float ih = istd_head[head];

    // zero the k-pad region of Qs/Ks once (re-staging never touches it)
    {
        int row = tid>>1, hf = tid&1;
        uint4 z = {0,0,0,0};
        *(uint4*)&Qs[row*40 + 16 + hf*8] = z;
        *(uint4*)&Ks[row*40 + 16 + hf*8] = z;
    }

    // stage Q (rows l0..l0+127) + per-row norms
    {
        int row = tid>>1, cg = tid&1;
        float qn2p = 0.f;
        float qv[8];
        #pragma unroll
        for(int cc=0;cc<8;cc++){
            int ch = h*16 + cg*8 + cc;
            float w_ = gq_w[ch]*istd, b_ = gq_b[ch]-mu*istd*gq_w[ch];
            float x = base[(size_t)ch*LSEQ + l0 + row];
            float v = x*w_ + b_;
            qv[cc] = v;
            qn2p += v*v;
        }
        uint4 pq;
        pq.x = packbf(qv[0],qv[1]); pq.y = packbf(qv[2],qv[3]);
        pq.z = packbf(qv[4],qv[5]); pq.w = packbf(qv[6],qv[7]);
        *(uint4*)&Qs[row*40 + cg*8] = pq;
        float oth = __shfl_xor(qn2p, 1);
        if(cg==0) bounds_l[row] = sqrtf(qn2p + oth);
    }

    // K max-norm over all 1024 m (Cauchy-Schwarz bound)
    {
        float kn2max = 0.f;
        #pragma unroll
        for(int j=0;j<4;j++){
            int m = tid + j*256;
            float s = 0.f;
            for(int c=0;c<16;c++){
                int ch = 128+h*16+c;
                float x = base[(size_t)ch*LSEQ + m];
                float kv = (x-mu)*istd*gq_w[ch]+gq_b[ch];
                s += kv*kv;
            }
            kn2max = fmaxf(kn2max, s);
        }
        #pragma unroll
        for(int d=1;d<64;d<<=1) kn2max = fmaxf(kn2max, __shfl_xor(kn2max,d));
        if(lane==0) sred4[wv] = kn2max;
    }
    __syncthreads();
    float kmax = sqrtf(fmaxf(fmaxf(sred4[0],sred4[1]),fmaxf(sred4[2],sred4[3])));

    // cached Q B-frags + per-row exp-shift
    bf16x8 qf[2];
    float B2[2]; int grow[2];
    #pragma unroll
    for(int t=0;t<2;t++){
        int rl = (2*wv+t)*16 + col;
        qf[t] = *(bf16x8*)&Qs[rl*40 + quad*8];
        B2[t] = bounds_l[rl]*kmax*ih;
        grow[t] = l0 + rl;
    }

    // hoisted staging coefficients
    int km_l = tid>>1, kg = tid&1;
    float kw8[8], kb8[8];
    #pragma unroll
    for(int cc=0;cc<8;cc++){
        int ch = 128+h*16+kg*8+cc;
        kw8[cc] = gq_w[ch]*istd;
        kb8[cc] = gq_b[ch]-mu*istd*gq_w[ch];
    }
    int vd = tid>>3, vmg = tid&7;
    float vw, vb;
    {
        int ch = 256+h*32+vd;
        vw = gq_w[ch]*istd;
        vb = gq_b[ch]-mu*istd*gq_w[ch];
    }
    const float* kp = base + (size_t)(128+h*16+kg*8)*LSEQ + km_l;
    const float* vp = base + (size_t)(256+h*32+vd)*LSEQ + vmg*16;

    f32x4 acc[2][2];
    #pragma unroll
    for(int t=0;t<2;t++){ acc[t][0]=(f32x4){0,0,0,0}; acc[t][1]=(f32x4){0,0,0,0}; }
    float ssum[2] = {0.f,0.f};
    const f32x4 zero4 = {0.f,0.f,0.f,0.f};

    for(int mc=0;mc<8;mc++){
        int M0 = mc*128;
        // stage K chunk (128 m x 16 c)
        {
            float kv[8];
            #pragma unroll
            for(int cc=0;cc<8;cc++)
                kv[cc] = kp[(size_t)cc*LSEQ + M0]*kw8[cc] + kb8[cc];
            uint4 pk;
            pk.x=packbf(kv[0],kv[1]); pk.y=packbf(kv[2],kv[3]);
            pk.z=packbf(kv[4],kv[5]); pk.w=packbf(kv[6],kv[7]);
            *(uint4*)&Ks[km_l*40 + kg*8] = pk;
        }
        // stage V chunk (32 d x 128 m)
        {
            float4 x0 = *(const float4*)&vp[M0];
            float4 x1 = *(const float4*)&vp[M0+4];
            float4 x2 = *(const float4*)&vp[M0+8];
            float4 x3 = *(const float4*)&vp[M0+12];
            uint4 p0, p1;
            p0.x = packbf(x0.x*vw+vb, x0.y*vw+vb);
            p0.y = packbf(x0.z*vw+vb, x0.w*vw+vb);
            p0.z = packbf(x1.x*vw+vb, x1.y*vw+vb);
            p0.w = packbf(x1.z*vw+vb, x1.w*vw+vb);
            p1.x = packbf(x2.x*vw+vb, x2.y*vw+vb);
            p1.y = packbf(x2.z*vw+vb, x2.w*vw+vb);
            p1.z = packbf(x3.x*vw+vb, x3.y*vw+vb);
            p1.w = packbf(x3.z*vw+vb, x3.w*vw+vb);
            *(uint4*)&Vs[vd*136 + vmg*16]     = p0;
            *(uint4*)&Vs[vd*136 + vmg*16 + 8] = p1;
        }
        __syncthreads();

        // S^T = K.Q^T -> exp -> P (wave-local rows)
        #pragma unroll
        for(int mt=0;mt<8;mt++){
            bf16x8 ak = *(bf16x8*)&Ks[(mt*16+col)*40 + quad*8];
            #pragma unroll
            for(int t=0;t<2;t++){
                f32x4 sc = __builtin_amdgcn_mfma_f32_16x16x32_bf16(ak, qf[t], zero4, 0,0,0);
                int mbase = M0 + mt*16 + quad*4;
                float pr[4];
                #pragma unroll
                for(int r=0;r<4;r++){
                    float e = __expf(fmaf(sc[r], ih, -B2[t]));
                    pr[r] = (mbase + r == grow[t]) ? 0.f : e;
                    ssum[t] += pr[r];
                }
                uint2 pw;
                pw.x = packbf(pr[0],pr[1]); pw.y = packbf(pr[2],pr[3]);
                *(uint2*)&Ps[((2*wv+t)*16+col)*152 + mt*16 + quad*4] = pw;
            }
        }
        // PV: out += P.V  (Ps rows wave-local; Vs covered by staging barrier)
        #pragma unroll
        for(int kk=0;kk<4;kk++){
            bf16x8 bv0 = *(bf16x8*)&Vs[( col)*136 + kk*32 + quad*8];
            bf16x8 bv1 = *(bf16x8*)&Vs[((16+col))*136 + kk*32 + quad*8];
            #pragma unroll
            for(int t=0;t<2;t++){
                bf16x8 ap = *(bf16x8*)&Ps[((2*wv+t)*16+col)*152 + kk*32 + quad*8];
                acc[t][0] = __builtin_amdgcn_mfma_f32_16x16x32_bf16(ap, bv0, acc[t][0], 0,0,0);
                acc[t][1] = __builtin_amdgcn_mfma_f32_16x16x32_bf16(ap, bv1, acc[t][1], 0,0,0);
            }
        }
        __syncthreads();
    }

    // row sums -> inverse
    #pragma unroll
    for(int t=0;t<2;t++){
        float v = ssum[t];
        v += __shfl_xor(v,16);
        v += __shfl_xor(v,32);
        if(quad==0) issum_l[(2*wv+t)*16+col] = v;
    }
    __syncthreads();
    if(tid<128) issum_l[tid] = 1.f/issum_l[tid];
    __syncthreads();

    // restage output (fp32) into Ps region for coalesced global write
    float* ep = (float*)Ps;
    #pragma unroll
    for(int t=0;t<2;t++)
        #pragma unroll
        for(int dt=0;dt<2;dt++)
            *(f32x4*)&ep[(dt*16+col)*132 + (2*wv+t)*16 + quad*4] = acc[t][dt];
    __syncthreads();

    float lsum=0.f, lsq=0.f;
    size_t obase = (size_t)n*262144 + (size_t)h*32*LSEQ + l0;
    #pragma unroll
    for(int t=0;t<16;t++){
        int idx = t*256 + tid;
        int d = idx>>7, row = idx&127;
        float y = ep[d*132+row]*issum_l[row];
        out[obase + (size_t)d*LSEQ + row] = y;
        lsum += y; lsq += y*y;
    }
    float* red = (float*)Ks;
    red[tid]=lsum; red[256+tid]=lsq;
    __syncthreads();
    for(int s=128;s>0;s>>=1){
        if(tid<s){ red[tid]+=red[tid+s]; red[256+tid]+=red[256+tid+s]; }
        __syncthreads();
    }
    if(tid==0){
        atomicAdd(&out_stats[2*n],   red[0]);
        atomicAdd(&out_stats[2*n+1], red[256]);
    }
}

// ---------------------------------------------------------------------------
// out = gelu(resid + groupnorm(x)) elementwise; c = channel of element.
// ---------------------------------------------------------------------------
__global__ __launch_bounds__(256) void ew_resid(
    const float* __restrict__ resid, const float* __restrict__ x,
    const float* __restrict__ stats,
    const float* __restrict__ gw, const float* __restrict__ gb,
    float cnt_inv, float* __restrict__ out)
{
    int idx = blockIdx.x*256 + threadIdx.x;   // float4 index
    int n = idx >> 16;                        // 65536 float4 per sample
    int c = (idx >> 8) & 255;
    float ss = stats[2*n], s2 = stats[2*n+1];
    float mu = ss*cnt_inv;
    float var = s2*cnt_inv - mu*mu;
    float istd = rsqrtf(var + 1e-5f);
    float w_ = gw[c], b_ = gb[c];
    float4 xv = ((const float4*)x)[idx];
    float4 rv = ((const float4*)resid)[idx];
    float4 ov;
    ov.x = gelu_f(rv.x + ((xv.x-mu)*istd*w_+b_));
    ov.y = gelu_f(rv.y + ((xv.y-mu)*istd*w_+b_));
    ov.z = gelu_f(rv.z + ((xv.z-mu)*istd*w_+b_));
    ov.w = gelu_f(rv.w + ((xv.w-mu)*istd*w_+b_));
    ((float4*)out)[idx] = ov;
}

// ---------------------------------------------------------------------------
extern "C" void kernel_launch(void* const* d_in, const int* in_sizes, int n_in,
                              void* d_out, int out_size, void* d_ws, size_t ws_size,
                              hipStream_t stream) {
    const float* f     = (const float*)d_in[0];
    const float* w_z   = (const float*)d_in[1];
    const float* gz_w  = (const float*)d_in[2];
    const float* gz_b  = (const float*)d_in[3];
    const float* w_qkv = (const float*)d_in[4];
    const float* gq_w  = (const float*)d_in[5];
    const float* gq_b  = (const float*)d_in[6];
    const float* w_out = (const float*)d_in[7];
    const float* go_w  = (const float*)d_in[8];
    const float* go_b  = (const float*)d_in[9];
    const float* w_f1  = (const float*)d_in[10];
    const float* g1_w  = (const float*)d_in[11];
    const float* g1_b  = (const float*)d_in[12];
    const float* w_f2  = (const float*)d_in[13];
    const float* g2_w  = (const float*)d_in[14];
    const float* g2_b  = (const float*)d_in[15];

    float* ws = (float*)d_ws;
    float* stats = ws;                 // 256 floats
    float* s_z    = stats + 0;
    float* s_qkv  = stats + 16;
    float* s_attn = stats + 32;
    float* s_x    = stats + 48;
    float* s_h1   = stats + 64;
    float* s_h2   = stats + 80;
    float* istdh  = stats + 96;        // 64
    const size_t SM = (size_t)256*1024;   // per-sample 256-ch tensor
    float* buf0 = ws + 256;            // 8*SM  : z0 -> attn_out -> f1 (buf3 alias)
    float* buf1 = buf0 + 8*SM;         // 8*2SM : qkv -> h1pre
    float* buf2 = buf1 + 16*SM;        // 8*SM  : x -> h2pre
    float* buf3 = buf0;                // f1 aliases buf0 (dead after K4)
    float* outp = (float*)d_out;

    hipMemsetAsync(stats, 0, 256*sizeof(float), stream);

    dim3 blk(256);
    // z0 = w_z @ gelu(f)
    gemm_mfma<<<dim3(16,4,8),blk,0,stream>>>(w_z, f, buf0,
        nullptr, nullptr, nullptr, 0.f, 1, 256, 256, s_z);
    // qkv = w_qkv @ gelu(gn(z0))
    gemm_mfma<<<dim3(16,8,8),blk,0,stream>>>(w_qkv, buf0, buf1,
        s_z, gz_w, gz_b, 1.f/262144.f, 1, 512, 256, s_qkv);
    // analytic per-head logit-LN istd
    head_stats<<<64,blk,0,stream>>>(buf1, s_qkv, gq_w, gq_b, istdh);
    // attention -> attn_out (overwrites z0)
    attn_kernel<<<512,blk,0,stream>>>(buf1, s_qkv, gq_w, gq_b, istdh, buf0, s_attn);
    // x = w_out @ gelu(ln(attn_out))
    gemm_mfma<<<dim3(16,4,8),blk,0,stream>>>(w_out, buf0, buf2,
        s_attn, nullptr, nullptr, 1.f/262144.f, 1, 256, 256, s_x);
    // f1 = gelu(f + gn_go(x))   (writes over attn_out region)
    ew_resid<<<2048,blk,0,stream>>>(f, buf2, s_x, go_w, go_b, 1.f/262144.f, buf3);
    // h1 = w_ffn1 @ f1
    gemm_mfma<<<dim3(16,8,8),blk,0,stream>>>(w_f1, buf3, buf1,
        nullptr, nullptr, nullptr, 0.f, 0, 512, 256, s_h1);
    // h2 = w_ffn2 @ gelu(gn_g1(h1))
    gemm_mfma<<<dim3(16,4,8),blk,0,stream>>>(w_f2, buf1, buf2,
        s_h1, g1_w, g1_b, 1.f/524288.f, 1, 256, 512, s_h2);
    // out = gelu(f1 + gn_g2(h2))
    ew_resid<<<2048,blk,0,stream>>>(buf3, buf2, s_h2, g2_w, g2_b, 1.f/262144.f, outp);
}

// Round 7
// 359.678 us; speedup vs baseline: 1.5564x; 1.3107x over previous
//
#include <hip/hip_runtime.h>

#define LSEQ 1024

typedef __attribute__((ext_vector_type(8))) short bf16x8;
typedef __attribute__((ext_vector_type(4))) float f32x4;

__device__ __forceinline__ float gelu_f(float x){
    return 0.5f*x*(1.0f+erff(x*0.7071067811865476f));
}

__device__ __forceinline__ unsigned f2bf1(float x){
    unsigned u = __float_as_uint(x);
    return (u + 0x7fffu + ((u>>16)&1u)) >> 16;
}
__device__ __forceinline__ unsigned packbf(float lo, float hi){
    return f2bf1(lo) | (f2bf1(hi)<<16);
}

// ---------------------------------------------------------------------------
// MFMA GEMM v2: C[n] = A (M,K) x transform(B[n]) (K,1024).
// transform = optional groupnorm (global stats) + affine + optional residual
// add (Bres) + optional gelu, fused into bf16 LDS staging.
// Register-prefetch of the next K-chunk across the barrier hides global
// latency; launch_bounds(256,2) caps at 128 VGPR (no spill, enough ILP).
// Accumulates per-sample sum/sumsq of outputs into out_stats.
// ---------------------------------------------------------------------------
__global__ __launch_bounds__(256,2) void gemm_mfma(
    const float* __restrict__ A,
    const float* __restrict__ B,
    const float* __restrict__ Bres,
    float* __restrict__ C,
    const float* __restrict__ in_stats,
    const float* __restrict__ gw,
    const float* __restrict__ gb,
    float in_cnt_inv, int apply_gelu,
    int M, int K,
    float* __restrict__ out_stats)
{
    __shared__ short As[64*40];   // [m][k]
    __shared__ short Bs[64*40];   // [l][k]

    int tid = threadIdx.x;
    int n  = blockIdx.z;
    int n0 = blockIdx.x*64;       // l offset
    int m0 = blockIdx.y*64;       // output-channel offset
    int wave = tid>>6, lane = tid&63;
    int col = lane&15, quad = lane>>4;

    float mu=0.f, istd=1.f;
    if (in_stats){
        float s1 = in_stats[2*n], s2 = in_stats[2*n+1];
        mu = s1*in_cnt_inv;
        float var = s2*in_cnt_inv - mu*mu;
        istd = rsqrtf(var + 1e-5f);
    }

    const float* Bn = B + (size_t)n*K*LSEQ;
    const float* Rn = Bres ? (Bres + (size_t)n*K*LSEQ) : nullptr;

    int sm = tid>>2,  sk = (tid&3)*8;   // A: row sm, k sk..sk+7
    int sl = tid&63,  scg = tid>>6;     // B: l sl, channels scg*8..+7

    f32x4 acc[4];
    #pragma unroll
    for(int t=0;t<4;t++) acc[t] = (f32x4){0.f,0.f,0.f,0.f};

    const float* ap = A + (size_t)(m0+sm)*K + sk;

    // ---- preload chunk 0 ----
    float4 a0 = *(const float4*)(ap);
    float4 a1 = *(const float4*)(ap+4);
    float bv[8], rv[8];
    #pragma unroll
    for(int cc=0;cc<8;cc++){
        int c = scg*8 + cc;
        bv[cc] = Bn[(size_t)c*LSEQ + n0 + sl];
        if(Rn) rv[cc] = Rn[(size_t)c*LSEQ + n0 + sl];
    }

    for(int k0=0; k0<K; k0+=32){
        // pack A
        uint4 pa;
        pa.x = packbf(a0.x,a0.y); pa.y = packbf(a0.z,a0.w);
        pa.z = packbf(a1.x,a1.y); pa.w = packbf(a1.z,a1.w);
        // transform + pack B
        uint4 pb;
        {
            float tv[8];
            #pragma unroll
            for(int cc=0;cc<8;cc++){
                int c = k0 + scg*8 + cc;
                float w_=1.f, b_=0.f;
                if (gw){ w_=gw[c]; b_=gb[c]; }
                float t = (bv[cc]-mu)*istd*w_ + b_;
                if (Rn) t += rv[cc];
                if (apply_gelu) t = gelu_f(t);
                tv[cc]=t;
            }
            pb.x = packbf(tv[0],tv[1]); pb.y = packbf(tv[2],tv[3]);
            pb.z = packbf(tv[4],tv[5]); pb.w = packbf(tv[6],tv[7]);
        }
        __syncthreads();   // prior-iter LDS consumers done
        *(uint4*)&As[sm*40 + sk] = pa;
        *(uint4*)&Bs[sl*40 + scg*8] = pb;
        __syncthreads();

        // prefetch next chunk (retires behind the MFMAs)
        if(k0+32 < K){
            a0 = *(const float4*)(ap + k0+32);
            a1 = *(const float4*)(ap + k0+36);
            #pragma unroll
            for(int cc=0;cc<8;cc++){
                int c = k0+32 + scg*8 + cc;
                bv[cc] = Bn[(size_t)c*LSEQ + n0 + sl];
                if(Rn) rv[cc] = Rn[(size_t)c*LSEQ + n0 + sl];
            }
        }

        bf16x8 af = *(bf16x8*)&As[(wave*16+col)*40 + quad*8];
        #pragma unroll
        for(int t=0;t<4;t++){
            bf16x8 bf = *(bf16x8*)&Bs[(t*16+col)*40 + quad*8];
            acc[t] = __builtin_amdgcn_mfma_f32_16x16x32_bf16(af, bf, acc[t], 0,0,0);
        }
    }

    __syncthreads();
    size_t cbase = (size_t)n*M*LSEQ;
    float lsum=0.f, lsq=0.f;
    #pragma unroll
    for(int t=0;t<4;t++){
        #pragma unroll
        for(int r=0;r<4;r++){
            int m = m0 + wave*16 + quad*4 + r;
            int l = n0 + t*16 + col;
            float v = acc[t][r];
            C[cbase + (size_t)m*LSEQ + l] = v;
            lsum += v; lsq += v*v;
        }
    }
    float* scr = (float*)As;
    scr[tid] = lsum; scr[256+tid] = lsq;
    __syncthreads();
    for(int s=128;s>0;s>>=1){
        if(tid<s){ scr[tid]+=scr[tid+s]; scr[256+tid]+=scr[256+tid+s]; }
        __syncthreads();
    }
    if(tid==0){
        atomicAdd(&out_stats[2*n],   scr[0]);
        atomicAdd(&out_stats[2*n+1], scr[256]);
    }
}

// ---------------------------------------------------------------------------
// head_cov: per (head, 128-pos chunk) partial 16x16 covariances of normalized
// q and k, plus per-channel sums. S2 of the LxL logit map = tr(Mk.Mq), so no
// pass over l x (16x16 matvec) is needed. 512 blocks -> full-chip parallel.
// ---------------------------------------------------------------------------
__global__ __launch_bounds__(256,2) void head_cov(
    const float* __restrict__ qkv,
    const float* __restrict__ s_qkv,
    const float* __restrict__ gq_w, const float* __restrict__ gq_b,
    float* __restrict__ covq, float* __restrict__ covk,
    float* __restrict__ sumq, float* __restrict__ sumk)
{
    __shared__ float Kq[16*132];
    __shared__ float Kk[16*132];
    int b = blockIdx.x;
    int head = b>>3, chunk = b&7;
    int n = head>>3, h = head&7;
    int tid = threadIdx.x;
    int m0 = chunk*128;

    float s1 = s_qkv[2*n], s2v = s_qkv[2*n+1];
    float mu  = s1*(1.f/524288.f);
    float var = s2v*(1.f/524288.f) - mu*mu;
    float istd = rsqrtf(var + 1e-5f);

    const float* base = qkv + (size_t)n*512*LSEQ;
    int m = tid&127, cg = tid>>7;
    #pragma unroll
    for(int cc=0;cc<8;cc++){
        int c = cg*8+cc;
        int chq = h*16+c, chk = 128+h*16+c;
        Kq[c*132+m] = (base[(size_t)chq*LSEQ+m0+m]-mu)*istd*gq_w[chq]+gq_b[chq];
        Kk[c*132+m] = (base[(size_t)chk*LSEQ+m0+m]-mu)*istd*gq_w[chk]+gq_b[chk];
    }
    __syncthreads();

    int i = tid>>4, j = tid&15;
    float q0=0,q1=0,q2=0,q3=0, k0=0,k1=0,k2=0,k3=0;
    for(int mm=0;mm<128;mm+=4){
        float4 qa = *(const float4*)&Kq[i*132+mm];
        float4 qb = *(const float4*)&Kq[j*132+mm];
        q0 += qa.x*qb.x; q1 += qa.y*qb.y; q2 += qa.z*qb.z; q3 += qa.w*qb.w;
        float4 ka = *(const float4*)&Kk[i*132+mm];
        float4 kb = *(const float4*)&Kk[j*132+mm];
        k0 += ka.x*kb.x; k1 += ka.y*kb.y; k2 += ka.z*kb.z; k3 += ka.w*kb.w;
    }
    atomicAdd(&covq[head*256 + i*16 + j], (q0+q1)+(q2+q3));
    atomicAdd(&covk[head*256 + i*16 + j], (k0+k1)+(k2+k3));

    if(i==0){
        float s=0.f;
        for(int mm=0;mm<128;mm+=4){
            float4 v = *(const float4*)&Kq[j*132+mm];
            s += (v.x+v.y)+(v.z+v.w);
        }
        atomicAdd(&sumq[head*16+j], s);
    }
    if(i==1){
        float s=0.f;
        for(int mm=0;mm<128;mm+=4){
            float4 v = *(const float4*)&Kk[j*132+mm];
            s += (v.x+v.y)+(v.z+v.w);
        }
        atomicAdd(&sumk[head*16+j], s);
    }
}

// ---------------------------------------------------------------------------
// head_fin: istd of the LxL logit map per head from the covariances.
// 1 block x 256 threads: 4 threads per head, each 64 of the 256 cov cells.
// ---------------------------------------------------------------------------
__global__ __launch_bounds__(256) void head_fin(
    const float* __restrict__ covq, const float* __restrict__ covk,
    const float* __restrict__ sumq, const float* __restrict__ sumk,
    float* __restrict__ istd_head)
{
    int tid = threadIdx.x;
    int head = tid>>2, part = tid&3;
    double S2 = 0.0;
    #pragma unroll 8
    for(int e=part*64; e<part*64+64; e++)
        S2 += (double)covq[head*256+e]*(double)covk[head*256+e];
    S2 += __shfl_xor(S2,1);
    S2 += __shfl_xor(S2,2);
    if(part==0){
        double S1 = 0.0;
        for(int c=0;c<16;c++) S1 += (double)sumq[head*16+c]*(double)sumk[head*16+c];
        double cnt = 1048576.0;
        double mean = S1/cnt;
        double v2 = S2/cnt - mean*mean;
        if(v2 < 0.0) v2 = 0.0;
        istd_head[head] = (float)(1.0/sqrt(v2 + 1e-5));
    }
}

// ---------------------------------------------------------------------------
// Attention v4 (unchanged from R6): MFMA flash attention with analytic
// logit-LN istd and Cauchy-Schwarz shift bound.
// ---------------------------------------------------------------------------
__global__ __launch_bounds__(256) void attn_kernel(
    const float* __restrict__ qkv,
    const float* __restrict__ s_qkv,
    const float* __restrict__ gq_w, const float* __restrict__ gq_b,
    const float* __restrict__ istd_head,
    float* __restrict__ out,
    float* __restrict__ out_stats)
{
    __shared__ short Qs[128*40];    // [row][c], c 0..15 real, 16..31 zero
    __shared__ short Ks[128*40];    // [m][c],   same padding
    __shared__ short Vs[32*136];    // [d][m]
    __shared__ short Ps[128*152];   // [row][m] bf16 P
    __shared__ float bounds_l[128];
    __shared__ float issum_l[128];
    __shared__ float sred4[4];

    int b = blockIdx.x;
    int head = b>>3, rb = b&7;
    int n = head>>3, h = head&7;
    int tid = threadIdx.x;
    int wv = tid>>6, lane = tid&63;
    int col = lane&15, quad = lane>>4;
    int l0 = rb*128;

    const float* base = qkv + (size_t)n*512*LSEQ;
    float s1 = s_qkv[2*n], s2v = s_qkv[2*n+1];
    float mu  = s1*(1.f/524288.f);
    float var = s2v*(1.f/524288.f) - mu*mu;
    float istd = rsqrtf(var + 1e-5f);
    float ih = istd_head[head];

    {
        int row = tid>>1, hf = tid&1;
        uint4 z = {0,0,0,0};
        *(uint4*)&Qs[row*40 + 16 + hf*8] = z;
        *(uint4*)&Ks[row*40 + 16 + hf*8] = z;
    }

    {
        int row = tid>>1, cg = tid&1;
        float qn2p = 0.f;
        float qv[8];
        #pragma unroll
        for(int cc=0;cc<8;cc++){
            int ch = h*16 + cg*8 + cc;
            float w_ = gq_w[ch]*istd, b_ = gq_b[ch]-mu*istd*gq_w[ch];
            float x = base[(size_t)ch*LSEQ + l0 + row];
            float v = x*w_ + b_;
            qv[cc] = v;
            qn2p += v*v;
        }
        uint4 pq;
        pq.x = packbf(qv[0],qv[1]); pq.y = packbf(qv[2],qv[3]);
        pq.z = packbf(qv[4],qv[5]); pq.w = packbf(qv[6],qv[7]);
        *(uint4*)&Qs[row*40 + cg*8] = pq;
        float oth = __shfl_xor(qn2p, 1);
        if(cg==0) bounds_l[row] = sqrtf(qn2p + oth);
    }

    {
        float kn2max = 0.f;
        #pragma unroll
        for(int j=0;j<4;j++){
            int m = tid + j*256;
            float s = 0.f;
            for(int c=0;c<16;c++){
                int ch = 128+h*16+c;
                float x = base[(size_t)ch*LSEQ + m];
                float kv = (x-mu)*istd*gq_w[ch]+gq_b[ch];
                s += kv*kv;
            }
            kn2max = fmaxf(kn2max, s);
        }
        #pragma unroll
        for(int d=1;d<64;d<<=1) kn2max = fmaxf(kn2max, __shfl_xor(kn2max,d));
        if(lane==0) sred4[wv] = kn2max;
    }
    __syncthreads();
    float kmax = sqrtf(fmaxf(fmaxf(sred4[0],sred4[1]),fmaxf(sred4[2],sred4[3])));

    bf16x8 qf[2];
    float B2[2]; int grow[2];
    #pragma unroll
    for(int t=0;t<2;t++){
        int rl = (2*wv+t)*16 + col;
        qf[t] = *(bf16x8*)&Qs[rl*40 + quad*8];
        B2[t] = bounds_l[rl]*kmax*ih;
        grow[t] = l0 + rl;
    }

    int km_l = tid>>1, kg = tid&1;
    float kw8[8], kb8[8];
    #pragma unroll
    for(int cc=0;cc<8;cc++){
        int ch = 128+h*16+kg*8+cc;
        kw8[cc] = gq_w[ch]*istd;
        kb8[cc] = gq_b[ch]-mu*istd*gq_w[ch];
    }
    int vd = tid>>3, vmg = tid&7;
    float vw, vb;
    {
        int ch = 256+h*32+vd;
        vw = gq_w[ch]*istd;
        vb = gq_b[ch]-mu*istd*gq_w[ch];
    }
    const float* kp = base + (size_t)(128+h*16+kg*8)*LSEQ + km_l;
    const float* vp = base + (size_t)(256+h*32+vd)*LSEQ + vmg*16;

    f32x4 acc[2][2];
    #pragma unroll
    for(int t=0;t<2;t++){ acc[t][0]=(f32x4){0,0,0,0}; acc[t][1]=(f32x4){0,0,0,0}; }
    float ssum[2] = {0.f,0.f};
    const f32x4 zero4 = {0.f,0.f,0.f,0.f};

    for(int mc=0;mc<8;mc++){
        int M0 = mc*128;
        {
            float kv[8];
            #pragma unroll
            for(int cc=0;cc<8;cc++)
                kv[cc] = kp[(size_t)cc*LSEQ + M0]*kw8[cc] + kb8[cc];
            uint4 pk;
            pk.x=packbf(kv[0],kv[1]); pk.y=packbf(kv[2],kv[3]);
            pk.z=packbf(kv[4],kv[5]); pk.w=packbf(kv[6],kv[7]);
            *(uint4*)&Ks[km_l*40 + kg*8] = pk;
        }
        {
            float4 x0 = *(const float4*)&vp[M0];
            float4 x1 = *(const float4*)&vp[M0+4];
            float4 x2 = *(const float4*)&vp[M0+8];
            float4 x3 = *(const float4*)&vp[M0+12];
            uint4 p0, p1;
            p0.x = packbf(x0.x*vw+vb, x0.y*vw+vb);
            p0.y = packbf(x0.z*vw+vb, x0.w*vw+vb);
            p0.z = packbf(x1.x*vw+vb, x1.y*vw+vb);
            p0.w = packbf(x1.z*vw+vb, x1.w*vw+vb);
            p1.x = packbf(x2.x*vw+vb, x2.y*vw+vb);
            p1.y = packbf(x2.z*vw+vb, x2.w*vw+vb);
            p1.z = packbf(x3.x*vw+vb, x3.y*vw+vb);
            p1.w = packbf(x3.z*vw+vb, x3.w*vw+vb);
            *(uint4*)&Vs[vd*136 + vmg*16]     = p0;
            *(uint4*)&Vs[vd*136 + vmg*16 + 8] = p1;
        }
        __syncthreads();

        #pragma unroll
        for(int mt=0;mt<8;mt++){
            bf16x8 ak = *(bf16x8*)&Ks[(mt*16+col)*40 + quad*8];
            #pragma unroll
            for(int t=0;t<2;t++){
                f32x4 sc = __builtin_amdgcn_mfma_f32_16x16x32_bf16(ak, qf[t], zero4, 0,0,0);
                int mbase = M0 + mt*16 + quad*4;
                float pr[4];
                #pragma unroll
                for(int r=0;r<4;r++){
                    float e = __expf(fmaf(sc[r], ih, -B2[t]));
                    pr[r] = (mbase + r == grow[t]) ? 0.f : e;
                    ssum[t] += pr[r];
                }
                uint2 pw;
                pw.x = packbf(pr[0],pr[1]); pw.y = packbf(pr[2],pr[3]);
                *(uint2*)&Ps[((2*wv+t)*16+col)*152 + mt*16 + quad*4] = pw;
            }
        }
        #pragma unroll
        for(int kk=0;kk<4;kk++){
            bf16x8 bv0 = *(bf16x8*)&Vs[( col)*136 + kk*32 + quad*8];
            bf16x8 bv1 = *(bf16x8*)&Vs[((16+col))*136 + kk*32 + quad*8];
            #pragma unroll
            for(int t=0;t<2;t++){
                bf16x8 ap = *(bf16x8*)&Ps[((2*wv+t)*16+col)*152 + kk*32 + quad*8];
                acc[t][0] = __builtin_amdgcn_mfma_f32_16x16x32_bf16(ap, bv0, acc[t][0], 0,0,0);
                acc[t][1] = __builtin_amdgcn_mfma_f32_16x16x32_bf16(ap, bv1, acc[t][1], 0,0,0);
            }
        }
        __syncthreads();
    }

    #pragma unroll
    for(int t=0;t<2;t++){
        float v = ssum[t];
        v += __shfl_xor(v,16);
        v += __shfl_xor(v,32);
        if(quad==0) issum_l[(2*wv+t)*16+col] = v;
    }
    __syncthreads();
    if(tid<128) issum_l[tid] = 1.f/issum_l[tid];
    __syncthreads();

    float* ep = (float*)Ps;
    #pragma unroll
    for(int t=0;t<2;t++)
        #pragma unroll
        for(int dt=0;dt<2;dt++)
            *(f32x4*)&ep[(dt*16+col)*132 + (2*wv+t)*16 + quad*4] = acc[t][dt];
    __syncthreads();

    float lsum=0.f, lsq=0.f;
    size_t obase = (size_t)n*262144 + (size_t)h*32*LSEQ + l0;
    #pragma unroll
    for(int t=0;t<16;t++){
        int idx = t*256 + tid;
        int d = idx>>7, row = idx&127;
        float y = ep[d*132+row]*issum_l[row];
        out[obase + (size_t)d*LSEQ + row] = y;
        lsum += y; lsq += y*y;
    }
    float* red = (float*)Ks;
    red[tid]=lsum; red[256+tid]=lsq;
    __syncthreads();
    for(int s=128;s>0;s>>=1){
        if(tid<s){ red[tid]+=red[tid+s]; red[256+tid]+=red[256+tid+s]; }
        __syncthreads();
    }
    if(tid==0){
        atomicAdd(&out_stats[2*n],   red[0]);
        atomicAdd(&out_stats[2*n+1], red[256]);
    }
}

// ---------------------------------------------------------------------------
// ew_final: out = gelu( f1 + gn_g2(h2) ) with f1 = gelu( f + gn_go(x) )
// recomputed on the fly (f1 is never materialized).
// ---------------------------------------------------------------------------
__global__ __launch_bounds__(256) void ew_final(
    const float* __restrict__ f, const float* __restrict__ x,
    const float* __restrict__ h2,
    const float* __restrict__ sx, const float* __restrict__ sh,
    const float* __restrict__ go_w, const float* __restrict__ go_b,
    const float* __restrict__ g2_w, const float* __restrict__ g2_b,
    float* __restrict__ out)
{
    int idx = blockIdx.x*256 + threadIdx.x;   // float4 index
    int n = idx >> 16;
    int c = (idx >> 8) & 255;
    float mux, isx, muh, ish;
    {
        float s1 = sx[2*n], s2 = sx[2*n+1];
        mux = s1*(1.f/262144.f);
        isx = rsqrtf(s2*(1.f/262144.f) - mux*mux + 1e-5f);
        float t1 = sh[2*n], t2 = sh[2*n+1];
        muh = t1*(1.f/262144.f);
        ish = rsqrtf(t2*(1.f/262144.f) - muh*muh + 1e-5f);
    }
    float wo = go_w[c]*isx, bo = go_b[c]-mux*isx*go_w[c];
    float w2 = g2_w[c]*ish, b2 = g2_b[c]-muh*ish*g2_w[c];
    float4 xv = ((const float4*)x)[idx];
    float4 fv = ((const float4*)f)[idx];
    float4 hv = ((const float4*)h2)[idx];
    float4 ov;
    float f1;
    f1 = gelu_f(fv.x + xv.x*wo+bo); ov.x = gelu_f(f1 + hv.x*w2+b2);
    f1 = gelu_f(fv.y + xv.y*wo+bo); ov.y = gelu_f(f1 + hv.y*w2+b2);
    f1 = gelu_f(fv.z + xv.z*wo+bo); ov.z = gelu_f(f1 + hv.z*w2+b2);
    f1 = gelu_f(fv.w + xv.w*wo+bo); ov.w = gelu_f(f1 + hv.w*w2+b2);
    ((float4*)out)[idx] = ov;
}

// ---------------------------------------------------------------------------
extern "C" void kernel_launch(void* const* d_in, const int* in_sizes, int n_in,
                              void* d_out, int out_size, void* d_ws, size_t ws_size,
                              hipStream_t stream) {
    const float* f     = (const float*)d_in[0];
    const float* w_z   = (const float*)d_in[1];
    const float* gz_w  = (const float*)d_in[2];
    const float* gz_b  = (const float*)d_in[3];
    const float* w_qkv = (const float*)d_in[4];
    const float* gq_w  = (const float*)d_in[5];
    const float* gq_b  = (const float*)d_in[6];
    const float* w_out = (const float*)d_in[7];
    const float* go_w  = (const float*)d_in[8];
    const float* go_b  = (const float*)d_in[9];
    const float* w_f1  = (const float*)d_in[10];
    const float* g1_w  = (const float*)d_in[11];
    const float* g1_b  = (const float*)d_in[12];
    const float* w_f2  = (const float*)d_in[13];
    const float* g2_w  = (const float*)d_in[14];
    const float* g2_b  = (const float*)d_in[15];

    float* ws = (float*)d_ws;
    float* stats = ws;                 // 256 floats
    float* s_z    = stats + 0;
    float* s_qkv  = stats + 16;
    float* s_attn = stats + 32;
    float* s_x    = stats + 48;
    float* s_h1   = stats + 64;
    float* s_h2   = stats + 80;
    float* istdh  = stats + 96;        // 64
    const size_t SM = (size_t)256*1024;
    float* buf0 = ws + 256;            // 8*SM  : z0 -> attn_out -> h2
    float* buf1 = buf0 + 8*SM;         // 16*SM : qkv -> h1
    float* buf2 = buf1 + 16*SM;        // 8*SM  : covs (pre-attn) -> x (persists)
    float* outp = (float*)d_out;

    // covariance scratch lives in buf2 (dead until the x-gemm writes it)
    float* covq = buf2;                // 64*256
    float* covk = buf2 + 16384;        // 64*256
    float* sumq = buf2 + 32768;        // 64*16
    float* sumk = buf2 + 33792;        // 64*16

    hipMemsetAsync(stats, 0, 256*sizeof(float), stream);
    hipMemsetAsync(covq, 0, 34816*sizeof(float), stream);

    dim3 blk(256);
    // z0 = w_z @ gelu(f)
    gemm_mfma<<<dim3(16,4,8),blk,0,stream>>>(w_z, f, nullptr, buf0,
        nullptr, nullptr, nullptr, 0.f, 1, 256, 256, s_z);
    // qkv = w_qkv @ gelu(gn(z0))
    gemm_mfma<<<dim3(16,8,8),blk,0,stream>>>(w_qkv, buf0, nullptr, buf1,
        s_z, gz_w, gz_b, 1.f/262144.f, 1, 512, 256, s_qkv);
    // per-head covariances + analytic logit-LN istd
    head_cov<<<512,blk,0,stream>>>(buf1, s_qkv, gq_w, gq_b, covq, covk, sumq, sumk);
    head_fin<<<1,blk,0,stream>>>(covq, covk, sumq, sumk, istdh);
    // attention -> attn_out (overwrites z0)
    attn_kernel<<<512,blk,0,stream>>>(buf1, s_qkv, gq_w, gq_b, istdh, buf0, s_attn);
    // x = w_out @ gelu(ln(attn_out))   (overwrites cov scratch)
    gemm_mfma<<<dim3(16,4,8),blk,0,stream>>>(w_out, buf0, nullptr, buf2,
        s_attn, nullptr, nullptr, 1.f/262144.f, 1, 256, 256, s_x);
    // h1 = w_ffn1 @ gelu(f + gn_go(x))   (ew fused into B-transform)
    gemm_mfma<<<dim3(16,8,8),blk,0,stream>>>(w_f1, buf2, f, buf1,
        s_x, go_w, go_b, 1.f/262144.f, 1, 512, 256, s_h1);
    // h2 = w_ffn2 @ gelu(gn_g1(h1))
    gemm_mfma<<<dim3(16,4,8),blk,0,stream>>>(w_f2, buf1, nullptr, buf0,
        s_h1, g1_w, g1_b, 1.f/524288.f, 1, 256, 512, s_h2);
    // out = gelu( gelu(f + gn_go(x)) + gn_g2(h2) )
    ew_final<<<2048,blk,0,stream>>>(f, buf2, buf0, s_x, s_h2,
        go_w, go_b, g2_w, g2_b, outp);
}